// Round 8
// baseline (100.588 us; speedup 1.0000x reference)
//
#include <hip/hip_runtime.h>
#include <math.h>

#define NPIX   131072      // 8*128*128
#define CCH    256
#define HW     16384       // 128*128
#define BSTR   4194304     // 256*16384 (features b-stride)
#define NUMC   21
#define KC     5376        // 21*256
#define NREP   16

typedef __attribute__((ext_vector_type(8))) short bf16x8;   // 8 bf16 (4 VGPRs)
typedef __attribute__((ext_vector_type(4))) float f32x4;

static __device__ __forceinline__ uint f2bf(float x) {      // f32 -> bf16 bits, RTNE
    uint u = __builtin_bit_cast(uint, x);
    return (u + 0x7FFFu + ((u >> 16) & 1u)) >> 16;
}
static __device__ __forceinline__ uint ohv(int lbl, int cls, uint iv) {
    return (lbl == cls) ? iv : 0u;                          // onehot*invn as bf16 bits
}

// ---------------- kernel 1: pseudo labels + per-class counts ----------------
__global__ __launch_bounds__(256) void k_labels(const int* __restrict__ labels,
                                                const float* __restrict__ outputs_old,
                                                int* __restrict__ lab,
                                                float* __restrict__ gcnt)
{
    __shared__ float cnt[NUMC];
    if (threadIdx.x < NUMC) cnt[threadIdx.x] = 0.f;
    __syncthreads();

    int p = blockIdx.x * 256 + threadIdx.x;
    int b = p >> 14;
    int rem = p & 16383;
    int h = rem >> 7;
    int w = rem & 127;
    int ld = labels[b * 262144 + (h * 4) * 512 + (w * 4)];
    int out = ld;
    if (ld == 0) {
        const float* oo = outputs_old + (size_t)b * BSTR + (size_t)(h * 4) * 512 + (w * 4);
        float v0 = oo[0];
        float best = (v0 < 0.7f) ? 0.0f : v0;
        int bi = 0;
        #pragma unroll
        for (int c = 1; c < 16; ++c) {
            float v = oo[(size_t)c * 262144];
            v = (v < 0.7f) ? 0.0f : v;
            if (v > best) { best = v; bi = c; }   // strict > == first-occurrence argmax
        }
        out = bi;
    }
    lab[p] = out;
    unsafeAtomicAdd(&cnt[out], 1.0f);
    __syncthreads();
    if (threadIdx.x < NUMC) unsafeAtomicAdd(&gcnt[threadIdx.x], cnt[threadIdx.x]);
}

// ---------------- kernel 2: fused norm + MFMA per-class sums ----------------
// invn folded into A (raw bf16 tile) -> ONE barrier/phase; 2-deep reg prefetch.
__global__ __launch_bounds__(256, 3) void k_msum(const float* __restrict__ fa,
                                                 const float* __restrict__ fo,
                                                 const int* __restrict__ lab,
                                                 float* __restrict__ partA,
                                                 float* __restrict__ partO)
{
    __shared__ ushort tile[2][32 * 256];   // raw bf16, (p,ch) at ((p>>3)*256+ch)*8 + (p&7)
    __shared__ float4 ssqP4[2][32];        // [parity][wave*8 + pixel-quad]
    __shared__ int    labS[256];

    const int t = threadIdx.x;
    const int w = t >> 6, l = t & 63;
    const int isO = blockIdx.x & 1;
    const float* __restrict__ src = isO ? fo : fa;
    float* part = isO ? partO : partA;

    const int pbase = (blockIdx.x >> 1) * 256;
    const int img   = pbase >> 14;
    const int hw0   = pbase & 16383;
    const float* g  = src + (size_t)img * BSTR + hw0;

    labS[t] = lab[pbase + t];

    const int chb = w * 8 + (l >> 3);   // channel base, +32*i (i=0..7)
    const int pq  = l & 7;              // pixel-quad within phase (px = pq*4 + r)

    f32x4 acc[2][4];
    #pragma unroll
    for (int m = 0; m < 2; ++m)
        #pragma unroll
        for (int n = 0; n < 4; ++n)
            acc[m][n] = (f32x4){0.f, 0.f, 0.f, 0.f};

#define ISSUE(buf, ph) do { \
    _Pragma("unroll") \
    for (int i_ = 0; i_ < 8; ++i_) \
        buf[i_] = *(const float4*)(g + (size_t)(chb + 32 * i_) * HW + (ph) * 32 + pq * 4); \
    } while (0)

#define PHASE(buf, ph, par, pf) do { \
    /* ssq partials over this thread's 8 channels x 4 px */ \
    float sx = 0.f, sy = 0.f, sz = 0.f, sw_ = 0.f; \
    _Pragma("unroll") \
    for (int i_ = 0; i_ < 8; ++i_) { \
        sx += buf[i_].x * buf[i_].x;  sy += buf[i_].y * buf[i_].y; \
        sz += buf[i_].z * buf[i_].z;  sw_ += buf[i_].w * buf[i_].w; \
    } \
    _Pragma("unroll") \
    for (int off_ = 8; off_ < 64; off_ <<= 1) { \
        sx += __shfl_xor(sx, off_, 64);  sy += __shfl_xor(sy, off_, 64); \
        sz += __shfl_xor(sz, off_, 64);  sw_ += __shfl_xor(sw_, off_, 64); \
    } \
    if (l < 8) ssqP4[par][w * 8 + l] = make_float4(sx, sy, sz, sw_); \
    /* stage RAW bf16 tile (no inv dependency) */ \
    _Pragma("unroll") \
    for (int i_ = 0; i_ < 8; ++i_) { \
        uint lo_ = f2bf(buf[i_].x) | (f2bf(buf[i_].y) << 16); \
        uint hi_ = f2bf(buf[i_].z) | (f2bf(buf[i_].w) << 16); \
        int ch_ = chb + 32 * i_; \
        *(uint2*)&tile[par][(((pq >> 1) * 256 + ch_) << 3) + ((pq & 1) << 2)] = \
            make_uint2(lo_, hi_); \
    } \
    if (pf) ISSUE(buf, (ph) + 2); \
    __syncthreads(); \
    /* invn for this lane's 8 A-matrix k-pixels */ \
    const int qd_ = (l >> 4) * 2; \
    float4 a0_ = ssqP4[par][qd_],      a1_ = ssqP4[par][8 + qd_]; \
    float4 a2_ = ssqP4[par][16 + qd_], a3_ = ssqP4[par][24 + qd_]; \
    float4 b0_ = ssqP4[par][qd_ + 1],  b1_ = ssqP4[par][9 + qd_]; \
    float4 b2_ = ssqP4[par][17 + qd_], b3_ = ssqP4[par][25 + qd_]; \
    uint iv0 = f2bf(1.f / fmaxf(sqrtf(a0_.x + a1_.x + a2_.x + a3_.x), 1e-12f)); \
    uint iv1 = f2bf(1.f / fmaxf(sqrtf(a0_.y + a1_.y + a2_.y + a3_.y), 1e-12f)); \
    uint iv2 = f2bf(1.f / fmaxf(sqrtf(a0_.z + a1_.z + a2_.z + a3_.z), 1e-12f)); \
    uint iv3 = f2bf(1.f / fmaxf(sqrtf(a0_.w + a1_.w + a2_.w + a3_.w), 1e-12f)); \
    uint iv4 = f2bf(1.f / fmaxf(sqrtf(b0_.x + b1_.x + b2_.x + b3_.x), 1e-12f)); \
    uint iv5 = f2bf(1.f / fmaxf(sqrtf(b0_.y + b1_.y + b2_.y + b3_.y), 1e-12f)); \
    uint iv6 = f2bf(1.f / fmaxf(sqrtf(b0_.z + b1_.z + b2_.z + b3_.z), 1e-12f)); \
    uint iv7 = f2bf(1.f / fmaxf(sqrtf(b0_.w + b1_.w + b2_.w + b3_.w), 1e-12f)); \
    /* A-frags: onehot * invn */ \
    int4 la_ = *(const int4*)&labS[(ph) * 32 + (l >> 4) * 8]; \
    int4 lb_ = *(const int4*)&labS[(ph) * 32 + (l >> 4) * 8 + 4]; \
    const int cls0_ = l & 15, cls1_ = 16 + (l & 15); \
    uint4 u0_, u1_; \
    u0_.x = ohv(la_.x, cls0_, iv0) | (ohv(la_.y, cls0_, iv1) << 16); \
    u0_.y = ohv(la_.z, cls0_, iv2) | (ohv(la_.w, cls0_, iv3) << 16); \
    u0_.z = ohv(lb_.x, cls0_, iv4) | (ohv(lb_.y, cls0_, iv5) << 16); \
    u0_.w = ohv(lb_.z, cls0_, iv6) | (ohv(lb_.w, cls0_, iv7) << 16); \
    u1_.x = ohv(la_.x, cls1_, iv0) | (ohv(la_.y, cls1_, iv1) << 16); \
    u1_.y = ohv(la_.z, cls1_, iv2) | (ohv(la_.w, cls1_, iv3) << 16); \
    u1_.z = ohv(lb_.x, cls1_, iv4) | (ohv(lb_.y, cls1_, iv5) << 16); \
    u1_.w = ohv(lb_.z, cls1_, iv6) | (ohv(lb_.w, cls1_, iv7) << 16); \
    bf16x8 A0_ = __builtin_bit_cast(bf16x8, u0_); \
    bf16x8 A1_ = __builtin_bit_cast(bf16x8, u1_); \
    _Pragma("unroll") \
    for (int n_ = 0; n_ < 4; ++n_) { \
        const int ct_ = w * 4 + n_; \
        const bf16x8 B_ = *(const bf16x8*)&tile[par][((l >> 4) * 256 + ct_ * 16 + (l & 15)) << 3]; \
        acc[0][n_] = __builtin_amdgcn_mfma_f32_16x16x32_bf16(A0_, B_, acc[0][n_], 0, 0, 0); \
        acc[1][n_] = __builtin_amdgcn_mfma_f32_16x16x32_bf16(A1_, B_, acc[1][n_], 0, 0, 0); \
    } \
    } while (0)

    float4 v0[8], v1[8];
    ISSUE(v0, 0);
    ISSUE(v1, 1);

    PHASE(v0, 0, 0, 1);
    PHASE(v1, 1, 1, 1);
    PHASE(v0, 2, 0, 1);
    PHASE(v1, 3, 1, 1);
    PHASE(v0, 4, 0, 1);
    PHASE(v1, 5, 1, 1);
    PHASE(v0, 6, 0, 0);
    PHASE(v1, 7, 1, 0);

#undef ISSUE
#undef PHASE

    // --- epilogue: D[cls][ch] -> replica atomics (col=lane&15, row=(lane>>4)*4+r) ---
    const int rep = (blockIdx.x >> 1) & (NREP - 1);
    #pragma unroll
    for (int m = 0; m < 2; ++m)
        #pragma unroll
        for (int n = 0; n < 4; ++n) {
            const int col = (w * 4 + n) * 16 + (l & 15);
            #pragma unroll
            for (int r = 0; r < 4; ++r) {
                const int row = m * 16 + (l >> 4) * 4 + r;
                if (row < NUMC)
                    unsafeAtomicAdd(&part[rep * KC + row * 256 + col], acc[m][n][r]);
            }
        }
}

// ---------------- kernel 3: finalize (tiny) ----------------
__global__ __launch_bounds__(256) void k_final(const float* __restrict__ partA,
                                               const float* __restrict__ partO,
                                               const float* __restrict__ gcnt,
                                               float* __restrict__ out)
{
    __shared__ float anc[NUMC * 260];
    __shared__ float con[NUMC * 260];
    __shared__ float adc[NUMC * 44];
    __shared__ float cntS[NUMC];
    __shared__ float rowloss[NUMC];
    __shared__ float rowvalid[NUMC];

    if (threadIdx.x < NUMC) cntS[threadIdx.x] = gcnt[threadIdx.x];
    __syncthreads();
    for (int i = threadIdx.x; i < KC; i += 256) {
        float sA = 0.f, sO = 0.f;
        #pragma unroll
        for (int r = 0; r < NREP; ++r) { sA += partA[r * KC + i]; sO += partO[r * KC + i]; }
        int k = i >> 8, c = i & 255;
        float cn = cntS[k];
        bool pr = cn > 0.f;
        float d = pr ? cn : 1.f;
        anc[k * 260 + c] = pr ? sA / d : 0.f;
        con[k * 260 + c] = pr ? sO / d : 0.f;
    }
    __syncthreads();
    // adc[k][j] = dot(anc_k, contrast_j)/T,  contrast = [anc; con]
    for (int pair = threadIdx.x; pair < NUMC * 2 * NUMC; pair += 256) {
        int k = pair / (2 * NUMC);
        int j = pair % (2 * NUMC);
        const float* ar = anc + k * 260;
        const float* br = (j < NUMC) ? (anc + j * 260) : (con + (j - NUMC) * 260);
        float s = 0.f;
        for (int c = 0; c < CCH; c += 4) {
            float4 a4 = *(const float4*)(ar + c);
            float4 b4 = *(const float4*)(br + c);
            s += a4.x * b4.x + a4.y * b4.y + a4.z * b4.z + a4.w * b4.w;
        }
        adc[k * 44 + j] = s / 0.07f;
    }
    __syncthreads();
    if (threadIdx.x < NUMC) {
        int k = threadIdx.x;
        bool pr = cntS[k] > 0.f;
        float neg = 0.f;       // faithful to source — negatives use UNshifted logits
        float mx = -1e30f;
        for (int j = 0; j < 2 * NUMC; ++j) {
            int cj = (j < NUMC) ? j : (j - NUMC);
            bool cp = cntS[cj] > 0.f;
            float v = adc[k * 44 + j];
            if (cp) {
                if (v > mx) mx = v;
                if (j != k && j != NUMC + k) neg += expf(v);
            }
        }
        float sh = adc[k * 44 + NUMC + k] - mx;
        float rl = -(sh - logf(expf(sh) + neg));
        rowloss[k] = pr ? rl : 0.f;
        rowvalid[k] = pr ? 1.f : 0.f;
    }
    __syncthreads();
    if (threadIdx.x == 0) {
        float s = 0.f, v = 0.f;
        for (int kk = 0; kk < NUMC; ++kk) { s += rowloss[kk]; v += rowvalid[kk]; }
        out[0] = s / fmaxf(v, 1.f);
    }
}

// ---------------- launch ----------------
extern "C" void kernel_launch(void* const* d_in, const int* in_sizes, int n_in,
                              void* d_out, int out_size, void* d_ws, size_t ws_size,
                              hipStream_t stream) {
    const int*   labels      = (const int*)  d_in[0];
    const float* feats_old   = (const float*)d_in[1];
    const float* feats       = (const float*)d_in[2];
    const float* outputs_old = (const float*)d_in[3];
    // d_in[4] (outputs) and d_in[5] (prototypes) are unused by the reference math.

    float* ws    = (float*)d_ws;
    int*   lab   = (int*)ws;                   // [131072]
    float* partA = ws + 131072;                // [16*5376]
    float* partO = partA + NREP * KC;          // [16*5376]
    float* gcnt  = partO + NREP * KC;          // [21]

    hipMemsetAsync(partA, 0, (size_t)(2 * NREP * KC + NUMC) * sizeof(float), stream);

    k_labels<<<NPIX / 256, 256, 0, stream>>>(labels, outputs_old, lab, gcnt);
    k_msum  <<<1024, 256, 0, stream>>>(feats, feats_old, lab, partA, partO);
    k_final <<<1, 256, 0, stream>>>(partA, partO, gcnt, (float*)d_out);
}

// Round 9
// 96.949 us; speedup vs baseline: 1.0375x; 1.0375x over previous
//
#include <hip/hip_runtime.h>
#include <math.h>

#define NPIX   131072      // 8*128*128
#define CCH    256
#define HW     16384       // 128*128
#define BSTR   4194304     // 256*16384 (features b-stride)
#define NUMC   21
#define KC     5376        // 21*256
#define NREP   16

typedef __attribute__((ext_vector_type(8))) short bf16x8;   // 8 bf16 (4 VGPRs)
typedef __attribute__((ext_vector_type(4))) float f32x4;

static __device__ __forceinline__ uint f2bf(float x) {      // f32 -> bf16 bits, RTNE
    uint u = __builtin_bit_cast(uint, x);
    return (u + 0x7FFFu + ((u >> 16) & 1u)) >> 16;
}
static __device__ __forceinline__ uint ohv(int lbl, int cls, uint iv) {
    return (lbl == cls) ? iv : 0u;                          // onehot*invn as bf16 bits
}
static __device__ __forceinline__ float rsq_fast(float x) { // single v_rsq_f32
#if __has_builtin(__builtin_amdgcn_rsqf)
    return __builtin_amdgcn_rsqf(x);
#else
    return rsqrtf(x);
#endif
}
// pack hi16(x),hi16(y) -> one word (bf16 trunc pair): D = {y[31:16], x[31:16]}
static __device__ __forceinline__ uint bfpack_trunc(float x, float y) {
    return __builtin_amdgcn_perm(__builtin_bit_cast(uint, y),
                                 __builtin_bit_cast(uint, x), 0x07060302u);
}

// ---------------- kernel 1: pseudo labels + per-class counts ----------------
__global__ __launch_bounds__(256) void k_labels(const int* __restrict__ labels,
                                                const float* __restrict__ outputs_old,
                                                int* __restrict__ lab,
                                                float* __restrict__ gcnt)
{
    __shared__ float cnt[NUMC];
    if (threadIdx.x < NUMC) cnt[threadIdx.x] = 0.f;
    __syncthreads();

    int p = blockIdx.x * 256 + threadIdx.x;
    int b = p >> 14;
    int rem = p & 16383;
    int h = rem >> 7;
    int w = rem & 127;
    int ld = labels[b * 262144 + (h * 4) * 512 + (w * 4)];
    int out = ld;
    if (ld == 0) {
        const float* oo = outputs_old + (size_t)b * BSTR + (size_t)(h * 4) * 512 + (w * 4);
        float v0 = oo[0];
        float best = (v0 < 0.7f) ? 0.0f : v0;
        int bi = 0;
        #pragma unroll
        for (int c = 1; c < 16; ++c) {
            float v = oo[(size_t)c * 262144];
            v = (v < 0.7f) ? 0.0f : v;
            if (v > best) { best = v; bi = c; }   // strict > == first-occurrence argmax
        }
        out = bi;
    }
    lab[p] = out;
    unsafeAtomicAdd(&cnt[out], 1.0f);
    __syncthreads();
    if (threadIdx.x < NUMC) unsafeAtomicAdd(&gcnt[threadIdx.x], cnt[threadIdx.x]);
}

// ---------------- kernel 2: fused norm + MFMA per-class sums ----------------
// invn folded into A (raw bf16 tile); ONE barrier/phase; 2-deep reg prefetch;
// v_rsq for invn (no IEEE div/sqrt sequences); v_perm bf16 pack for staging.
__global__ __launch_bounds__(256, 3) void k_msum(const float* __restrict__ fa,
                                                 const float* __restrict__ fo,
                                                 const int* __restrict__ lab,
                                                 float* __restrict__ partA,
                                                 float* __restrict__ partO)
{
    __shared__ ushort tile[2][32 * 256];   // raw bf16, (p,ch) at ((p>>3)*256+ch)*8 + (p&7)
    __shared__ float4 ssqP4[2][32];        // [parity][wave*8 + pixel-quad]
    __shared__ int    labS[256];

    const int t = threadIdx.x;
    const int w = t >> 6, l = t & 63;
    const int isO = blockIdx.x & 1;
    const float* __restrict__ src = isO ? fo : fa;
    float* part = isO ? partO : partA;

    const int pbase = (blockIdx.x >> 1) * 256;
    const int img   = pbase >> 14;
    const int hw0   = pbase & 16383;
    const float* g  = src + (size_t)img * BSTR + hw0;

    labS[t] = lab[pbase + t];

    const int chb = w * 8 + (l >> 3);   // channel base, +32*i (i=0..7)
    const int pq  = l & 7;              // pixel-quad within phase (px = pq*4 + r)

    f32x4 acc[2][4];
    #pragma unroll
    for (int m = 0; m < 2; ++m)
        #pragma unroll
        for (int n = 0; n < 4; ++n)
            acc[m][n] = (f32x4){0.f, 0.f, 0.f, 0.f};

#define ISSUE(buf, ph) do { \
    _Pragma("unroll") \
    for (int i_ = 0; i_ < 8; ++i_) \
        buf[i_] = *(const float4*)(g + (size_t)(chb + 32 * i_) * HW + (ph) * 32 + pq * 4); \
    } while (0)

#define PHASE(buf, ph, par, pf) do { \
    /* ssq partials over this thread's 8 channels x 4 px */ \
    float sx = 0.f, sy = 0.f, sz = 0.f, sw_ = 0.f; \
    _Pragma("unroll") \
    for (int i_ = 0; i_ < 8; ++i_) { \
        sx += buf[i_].x * buf[i_].x;  sy += buf[i_].y * buf[i_].y; \
        sz += buf[i_].z * buf[i_].z;  sw_ += buf[i_].w * buf[i_].w; \
    } \
    _Pragma("unroll") \
    for (int off_ = 8; off_ < 64; off_ <<= 1) { \
        sx += __shfl_xor(sx, off_, 64);  sy += __shfl_xor(sy, off_, 64); \
        sz += __shfl_xor(sz, off_, 64);  sw_ += __shfl_xor(sw_, off_, 64); \
    } \
    if (l < 8) ssqP4[par][w * 8 + l] = make_float4(sx, sy, sz, sw_); \
    /* stage RAW bf16 tile (trunc pack via v_perm, 1 instr per 2 elems) */ \
    _Pragma("unroll") \
    for (int i_ = 0; i_ < 8; ++i_) { \
        uint lo_ = bfpack_trunc(buf[i_].x, buf[i_].y); \
        uint hi_ = bfpack_trunc(buf[i_].z, buf[i_].w); \
        int ch_ = chb + 32 * i_; \
        *(uint2*)&tile[par][(((pq >> 1) * 256 + ch_) << 3) + ((pq & 1) << 2)] = \
            make_uint2(lo_, hi_); \
    } \
    if (pf) ISSUE(buf, (ph) + 2); \
    __syncthreads(); \
    /* invn for this lane's 8 A-matrix k-pixels: v_rsq, no div sequence */ \
    const int qd_ = (l >> 4) * 2; \
    float4 a0_ = ssqP4[par][qd_],      a1_ = ssqP4[par][8 + qd_]; \
    float4 a2_ = ssqP4[par][16 + qd_], a3_ = ssqP4[par][24 + qd_]; \
    float4 b0_ = ssqP4[par][qd_ + 1],  b1_ = ssqP4[par][9 + qd_]; \
    float4 b2_ = ssqP4[par][17 + qd_], b3_ = ssqP4[par][25 + qd_]; \
    uint iv0 = f2bf(rsq_fast(fmaxf(a0_.x + a1_.x + a2_.x + a3_.x, 1e-24f))); \
    uint iv1 = f2bf(rsq_fast(fmaxf(a0_.y + a1_.y + a2_.y + a3_.y, 1e-24f))); \
    uint iv2 = f2bf(rsq_fast(fmaxf(a0_.z + a1_.z + a2_.z + a3_.z, 1e-24f))); \
    uint iv3 = f2bf(rsq_fast(fmaxf(a0_.w + a1_.w + a2_.w + a3_.w, 1e-24f))); \
    uint iv4 = f2bf(rsq_fast(fmaxf(b0_.x + b1_.x + b2_.x + b3_.x, 1e-24f))); \
    uint iv5 = f2bf(rsq_fast(fmaxf(b0_.y + b1_.y + b2_.y + b3_.y, 1e-24f))); \
    uint iv6 = f2bf(rsq_fast(fmaxf(b0_.z + b1_.z + b2_.z + b3_.z, 1e-24f))); \
    uint iv7 = f2bf(rsq_fast(fmaxf(b0_.w + b1_.w + b2_.w + b3_.w, 1e-24f))); \
    /* A-frags: onehot * invn */ \
    int4 la_ = *(const int4*)&labS[(ph) * 32 + (l >> 4) * 8]; \
    int4 lb_ = *(const int4*)&labS[(ph) * 32 + (l >> 4) * 8 + 4]; \
    const int cls0_ = l & 15, cls1_ = 16 + (l & 15); \
    uint4 u0_, u1_; \
    u0_.x = ohv(la_.x, cls0_, iv0) | (ohv(la_.y, cls0_, iv1) << 16); \
    u0_.y = ohv(la_.z, cls0_, iv2) | (ohv(la_.w, cls0_, iv3) << 16); \
    u0_.z = ohv(lb_.x, cls0_, iv4) | (ohv(lb_.y, cls0_, iv5) << 16); \
    u0_.w = ohv(lb_.z, cls0_, iv6) | (ohv(lb_.w, cls0_, iv7) << 16); \
    u1_.x = ohv(la_.x, cls1_, iv0) | (ohv(la_.y, cls1_, iv1) << 16); \
    u1_.y = ohv(la_.z, cls1_, iv2) | (ohv(la_.w, cls1_, iv3) << 16); \
    u1_.z = ohv(lb_.x, cls1_, iv4) | (ohv(lb_.y, cls1_, iv5) << 16); \
    u1_.w = ohv(lb_.z, cls1_, iv6) | (ohv(lb_.w, cls1_, iv7) << 16); \
    bf16x8 A0_ = __builtin_bit_cast(bf16x8, u0_); \
    bf16x8 A1_ = __builtin_bit_cast(bf16x8, u1_); \
    _Pragma("unroll") \
    for (int n_ = 0; n_ < 4; ++n_) { \
        const int ct_ = w * 4 + n_; \
        const bf16x8 B_ = *(const bf16x8*)&tile[par][((l >> 4) * 256 + ct_ * 16 + (l & 15)) << 3]; \
        acc[0][n_] = __builtin_amdgcn_mfma_f32_16x16x32_bf16(A0_, B_, acc[0][n_], 0, 0, 0); \
        acc[1][n_] = __builtin_amdgcn_mfma_f32_16x16x32_bf16(A1_, B_, acc[1][n_], 0, 0, 0); \
    } \
    } while (0)

    float4 v0[8], v1[8];
    ISSUE(v0, 0);
    ISSUE(v1, 1);

    PHASE(v0, 0, 0, 1);
    PHASE(v1, 1, 1, 1);
    PHASE(v0, 2, 0, 1);
    PHASE(v1, 3, 1, 1);
    PHASE(v0, 4, 0, 1);
    PHASE(v1, 5, 1, 1);
    PHASE(v0, 6, 0, 0);
    PHASE(v1, 7, 1, 0);

#undef ISSUE
#undef PHASE

    // --- epilogue: D[cls][ch] -> replica atomics (col=lane&15, row=(lane>>4)*4+r) ---
    const int rep = (blockIdx.x >> 1) & (NREP - 1);
    #pragma unroll
    for (int m = 0; m < 2; ++m)
        #pragma unroll
        for (int n = 0; n < 4; ++n) {
            const int col = (w * 4 + n) * 16 + (l & 15);
            #pragma unroll
            for (int r = 0; r < 4; ++r) {
                const int row = m * 16 + (l >> 4) * 4 + r;
                if (row < NUMC)
                    unsafeAtomicAdd(&part[rep * KC + row * 256 + col], acc[m][n][r]);
            }
        }
}

// ---------------- kernel 3: finalize (tiny) ----------------
__global__ __launch_bounds__(256) void k_final(const float* __restrict__ partA,
                                               const float* __restrict__ partO,
                                               const float* __restrict__ gcnt,
                                               float* __restrict__ out)
{
    __shared__ float anc[NUMC * 260];
    __shared__ float con[NUMC * 260];
    __shared__ float adc[NUMC * 44];
    __shared__ float cntS[NUMC];
    __shared__ float rowloss[NUMC];
    __shared__ float rowvalid[NUMC];

    if (threadIdx.x < NUMC) cntS[threadIdx.x] = gcnt[threadIdx.x];
    __syncthreads();
    for (int i = threadIdx.x; i < KC; i += 256) {
        float sA = 0.f, sO = 0.f;
        #pragma unroll
        for (int r = 0; r < NREP; ++r) { sA += partA[r * KC + i]; sO += partO[r * KC + i]; }
        int k = i >> 8, c = i & 255;
        float cn = cntS[k];
        bool pr = cn > 0.f;
        float d = pr ? cn : 1.f;
        anc[k * 260 + c] = pr ? sA / d : 0.f;
        con[k * 260 + c] = pr ? sO / d : 0.f;
    }
    __syncthreads();
    // adc[k][j] = dot(anc_k, contrast_j)/T,  contrast = [anc; con]
    for (int pair = threadIdx.x; pair < NUMC * 2 * NUMC; pair += 256) {
        int k = pair / (2 * NUMC);
        int j = pair % (2 * NUMC);
        const float* ar = anc + k * 260;
        const float* br = (j < NUMC) ? (anc + j * 260) : (con + (j - NUMC) * 260);
        float s = 0.f;
        for (int c = 0; c < CCH; c += 4) {
            float4 a4 = *(const float4*)(ar + c);
            float4 b4 = *(const float4*)(br + c);
            s += a4.x * b4.x + a4.y * b4.y + a4.z * b4.z + a4.w * b4.w;
        }
        adc[k * 44 + j] = s / 0.07f;
    }
    __syncthreads();
    if (threadIdx.x < NUMC) {
        int k = threadIdx.x;
        bool pr = cntS[k] > 0.f;
        float neg = 0.f;       // faithful to source — negatives use UNshifted logits
        float mx = -1e30f;
        for (int j = 0; j < 2 * NUMC; ++j) {
            int cj = (j < NUMC) ? j : (j - NUMC);
            bool cp = cntS[cj] > 0.f;
            float v = adc[k * 44 + j];
            if (cp) {
                if (v > mx) mx = v;
                if (j != k && j != NUMC + k) neg += expf(v);
            }
        }
        float sh = adc[k * 44 + NUMC + k] - mx;
        float rl = -(sh - logf(expf(sh) + neg));
        rowloss[k] = pr ? rl : 0.f;
        rowvalid[k] = pr ? 1.f : 0.f;
    }
    __syncthreads();
    if (threadIdx.x == 0) {
        float s = 0.f, v = 0.f;
        for (int kk = 0; kk < NUMC; ++kk) { s += rowloss[kk]; v += rowvalid[kk]; }
        out[0] = s / fmaxf(v, 1.f);
    }
}

// ---------------- launch ----------------
extern "C" void kernel_launch(void* const* d_in, const int* in_sizes, int n_in,
                              void* d_out, int out_size, void* d_ws, size_t ws_size,
                              hipStream_t stream) {
    const int*   labels      = (const int*)  d_in[0];
    const float* feats_old   = (const float*)d_in[1];
    const float* feats       = (const float*)d_in[2];
    const float* outputs_old = (const float*)d_in[3];
    // d_in[4] (outputs) and d_in[5] (prototypes) are unused by the reference math.

    float* ws    = (float*)d_ws;
    int*   lab   = (int*)ws;                   // [131072]
    float* partA = ws + 131072;                // [16*5376]
    float* partO = partA + NREP * KC;          // [16*5376]
    float* gcnt  = partO + NREP * KC;          // [21]

    hipMemsetAsync(partA, 0, (size_t)(2 * NREP * KC + NUMC) * sizeof(float), stream);

    k_labels<<<NPIX / 256, 256, 0, stream>>>(labels, outputs_old, lab, gcnt);
    k_msum  <<<1024, 256, 0, stream>>>(feats, feats_old, lab, partA, partO);
    k_final <<<1, 256, 0, stream>>>(partA, partO, gcnt, (float*)d_out);
}

// Round 10
// 96.495 us; speedup vs baseline: 1.0424x; 1.0047x over previous
//
#include <hip/hip_runtime.h>
#include <math.h>

#define NPIX   131072      // 8*128*128
#define CCH    256
#define HW     16384       // 128*128
#define BSTR   4194304     // 256*16384 (features b-stride)
#define NUMC   21
#define KC     5376        // 21*256
#define NREP   16

typedef __attribute__((ext_vector_type(8))) short bf16x8;   // 8 bf16 (4 VGPRs)
typedef __attribute__((ext_vector_type(4))) float f32x4;

static __device__ __forceinline__ uint f2bf(float x) {      // f32 -> bf16 bits, RTNE
    uint u = __builtin_bit_cast(uint, x);
    return (u + 0x7FFFu + ((u >> 16) & 1u)) >> 16;
}
static __device__ __forceinline__ uint ohv(int lbl, int cls, uint iv) {
    return (lbl == cls) ? iv : 0u;                          // onehot*invn as bf16 bits
}
static __device__ __forceinline__ float rsq_fast(float x) { // single v_rsq_f32
#if __has_builtin(__builtin_amdgcn_rsqf)
    return __builtin_amdgcn_rsqf(x);
#else
    return rsqrtf(x);
#endif
}
// pack hi16(x),hi16(y) -> one word (bf16 trunc pair)
static __device__ __forceinline__ uint bfpack_trunc(float x, float y) {
    return __builtin_amdgcn_perm(__builtin_bit_cast(uint, y),
                                 __builtin_bit_cast(uint, x), 0x07060302u);
}

// ---------------- kernel 1: pseudo labels + per-class counts ----------------
__global__ __launch_bounds__(256) void k_labels(const int* __restrict__ labels,
                                                const float* __restrict__ outputs_old,
                                                int* __restrict__ lab,
                                                float* __restrict__ gcnt)
{
    __shared__ float cnt[NUMC];
    if (threadIdx.x < NUMC) cnt[threadIdx.x] = 0.f;
    __syncthreads();

    int p = blockIdx.x * 256 + threadIdx.x;
    int b = p >> 14;
    int rem = p & 16383;
    int h = rem >> 7;
    int w = rem & 127;
    int ld = labels[b * 262144 + (h * 4) * 512 + (w * 4)];
    int out = ld;
    if (ld == 0) {
        const float* oo = outputs_old + (size_t)b * BSTR + (size_t)(h * 4) * 512 + (w * 4);
        float v0 = oo[0];
        float best = (v0 < 0.7f) ? 0.0f : v0;
        int bi = 0;
        #pragma unroll
        for (int c = 1; c < 16; ++c) {
            float v = oo[(size_t)c * 262144];
            v = (v < 0.7f) ? 0.0f : v;
            if (v > best) { best = v; bi = c; }   // strict > == first-occurrence argmax
        }
        out = bi;
    }
    lab[p] = out;
    unsafeAtomicAdd(&cnt[out], 1.0f);
    __syncthreads();
    if (threadIdx.x < NUMC) unsafeAtomicAdd(&gcnt[threadIdx.x], cnt[threadIdx.x]);
}

// ---------------- kernel 2: hw-contiguous stream + MFMA per-class sums -------
// Block = 256 px of one tensor (2 chunks x 128 px), 4 waves. Staging loads are
// CONTIGUOUS (wave-load = 2x512B segments) -> fixes the R6-R9 2.6 TB/s wall.
// ssq is lane-local (zero shuffles). bf16 tile [256ch][128px] XOR-swizzled
// (write AND read, same involution). MFMA: D[cls][ch] += onehot*invn x tile.
__global__ __launch_bounds__(256, 2) void k_msum(const float* __restrict__ fa,
                                                 const float* __restrict__ fo,
                                                 const int* __restrict__ lab,
                                                 float* __restrict__ partA,
                                                 float* __restrict__ partO)
{
    __shared__ ushort tileB[CCH * 128];   // 64 KB, row=ch (256B), XOR-swizzled
    __shared__ float  ssqP[4][128];       // per-wave ssq partials
    __shared__ float  invnS[128];
    __shared__ int    labS[256];

    const int t = threadIdx.x;
    const int w = t >> 6, l = t & 63;
    const int isO = blockIdx.x & 1;
    const float* __restrict__ src = isO ? fo : fa;
    float* part = isO ? partO : partA;

    const int pbase = (blockIdx.x >> 1) * 256;
    const int img   = pbase >> 14;
    const int hw0   = pbase & 16383;
    const float* g  = src + (size_t)img * BSTR + hw0;

    labS[t] = lab[pbase + t];

    f32x4 acc[2][4];
    #pragma unroll
    for (int m = 0; m < 2; ++m)
        #pragma unroll
        for (int n = 0; n < 4; ++n)
            acc[m][n] = (f32x4){0.f, 0.f, 0.f, 0.f};

// contiguous wave-load: lanes 0-31 channel 2i+0, lanes 32-63 channel 2i+1,
// each lane 4 consecutive px -> 2 x 512B segments per instruction.
#define LOADB(B, i0) do { \
    _Pragma("unroll") \
    for (int i_ = 0; i_ < 8; ++i_) \
        B[i_] = *(const float4*)(gc + (size_t)(w * 64 + 2 * ((i0) + i_) + (l >> 5)) * HW \
                                 + (l & 31) * 4); \
    } while (0)

// process: lane-local ssq accum + bf16 pack + swizzled LDS store (8B)
#define PROCB(B, i0) do { \
    _Pragma("unroll") \
    for (int i_ = 0; i_ < 8; ++i_) { \
        float4 v_ = B[i_]; \
        s4.x += v_.x * v_.x;  s4.y += v_.y * v_.y; \
        s4.z += v_.z * v_.z;  s4.w += v_.w * v_.w; \
        int ch_ = w * 64 + 2 * ((i0) + i_) + (l >> 5); \
        uint lo_ = bfpack_trunc(v_.x, v_.y); \
        uint hi_ = bfpack_trunc(v_.z, v_.w); \
        *(uint2*)((char*)tileB + ch_ * 256 + ((((l & 31) * 8)) ^ ((ch_ & 7) << 4))) = \
            make_uint2(lo_, hi_); \
    } \
    } while (0)

#define KSTEP(c2, ks) do { \
    float4 ivA_ = *(const float4*)&invnS[(ks) * 32 + (l >> 4) * 8]; \
    float4 ivB_ = *(const float4*)&invnS[(ks) * 32 + (l >> 4) * 8 + 4]; \
    uint iv0 = f2bf(ivA_.x), iv1 = f2bf(ivA_.y), iv2 = f2bf(ivA_.z), iv3 = f2bf(ivA_.w); \
    uint iv4 = f2bf(ivB_.x), iv5 = f2bf(ivB_.y), iv6 = f2bf(ivB_.z), iv7 = f2bf(ivB_.w); \
    int4 la_ = *(const int4*)&labS[(c2) * 128 + (ks) * 32 + (l >> 4) * 8]; \
    int4 lb_ = *(const int4*)&labS[(c2) * 128 + (ks) * 32 + (l >> 4) * 8 + 4]; \
    const int cls0_ = l & 15, cls1_ = 16 + (l & 15); \
    uint4 u0_, u1_; \
    u0_.x = ohv(la_.x, cls0_, iv0) | (ohv(la_.y, cls0_, iv1) << 16); \
    u0_.y = ohv(la_.z, cls0_, iv2) | (ohv(la_.w, cls0_, iv3) << 16); \
    u0_.z = ohv(lb_.x, cls0_, iv4) | (ohv(lb_.y, cls0_, iv5) << 16); \
    u0_.w = ohv(lb_.z, cls0_, iv6) | (ohv(lb_.w, cls0_, iv7) << 16); \
    u1_.x = ohv(la_.x, cls1_, iv0) | (ohv(la_.y, cls1_, iv1) << 16); \
    u1_.y = ohv(la_.z, cls1_, iv2) | (ohv(la_.w, cls1_, iv3) << 16); \
    u1_.z = ohv(lb_.x, cls1_, iv4) | (ohv(lb_.y, cls1_, iv5) << 16); \
    u1_.w = ohv(lb_.z, cls1_, iv6) | (ohv(lb_.w, cls1_, iv7) << 16); \
    bf16x8 A0_ = __builtin_bit_cast(bf16x8, u0_); \
    bf16x8 A1_ = __builtin_bit_cast(bf16x8, u1_); \
    _Pragma("unroll") \
    for (int n_ = 0; n_ < 4; ++n_) { \
        const int chrow_ = (w * 4 + n_) * 16 + (l & 15); \
        const bf16x8 B_ = *(const bf16x8*)((const char*)tileB + chrow_ * 256 \
                            + (((ks) * 64 + (l >> 4) * 16) ^ ((chrow_ & 7) << 4))); \
        acc[0][n_] = __builtin_amdgcn_mfma_f32_16x16x32_bf16(A0_, B_, acc[0][n_], 0, 0, 0); \
        acc[1][n_] = __builtin_amdgcn_mfma_f32_16x16x32_bf16(A1_, B_, acc[1][n_], 0, 0, 0); \
    } \
    } while (0)

#define CHUNK(c2, LAST) do { \
    const float* gc = g + (c2) * 128; \
    float4 s4 = {0.f, 0.f, 0.f, 0.f}; \
    float4 bufA[8], bufB[8]; \
    LOADB(bufA, 0);  LOADB(bufB, 8); \
    PROCB(bufA, 0);  LOADB(bufA, 16); \
    PROCB(bufB, 8);  LOADB(bufB, 24); \
    PROCB(bufA, 16); PROCB(bufB, 24); \
    s4.x += __shfl_xor(s4.x, 32, 64);  s4.y += __shfl_xor(s4.y, 32, 64); \
    s4.z += __shfl_xor(s4.z, 32, 64);  s4.w += __shfl_xor(s4.w, 32, 64); \
    if (l < 32) *(float4*)&ssqP[w][l * 4] = s4; \
    __syncthreads(); \
    if (t < 128) { \
        float ss_ = ssqP[0][t] + ssqP[1][t] + ssqP[2][t] + ssqP[3][t]; \
        invnS[t] = rsq_fast(fmaxf(ss_, 1e-24f)); \
    } \
    __syncthreads(); \
    KSTEP(c2, 0); KSTEP(c2, 1); KSTEP(c2, 2); KSTEP(c2, 3); \
    if (!(LAST)) __syncthreads(); \
    } while (0)

    CHUNK(0, 0);
    CHUNK(1, 1);

#undef LOADB
#undef PROCB
#undef KSTEP
#undef CHUNK

    // --- epilogue: D[cls][ch] -> replica atomics (col=lane&15, row=(lane>>4)*4+r) ---
    const int rep = (blockIdx.x >> 1) & (NREP - 1);
    #pragma unroll
    for (int m = 0; m < 2; ++m)
        #pragma unroll
        for (int n = 0; n < 4; ++n) {
            const int col = (w * 4 + n) * 16 + (l & 15);
            #pragma unroll
            for (int r = 0; r < 4; ++r) {
                const int row = m * 16 + (l >> 4) * 4 + r;
                if (row < NUMC)
                    unsafeAtomicAdd(&part[rep * KC + row * 256 + col], acc[m][n][r]);
            }
        }
}

// ---------------- kernel 3: finalize (tiny) ----------------
__global__ __launch_bounds__(256) void k_final(const float* __restrict__ partA,
                                               const float* __restrict__ partO,
                                               const float* __restrict__ gcnt,
                                               float* __restrict__ out)
{
    __shared__ float anc[NUMC * 260];
    __shared__ float con[NUMC * 260];
    __shared__ float adc[NUMC * 44];
    __shared__ float cntS[NUMC];
    __shared__ float rowloss[NUMC];
    __shared__ float rowvalid[NUMC];

    if (threadIdx.x < NUMC) cntS[threadIdx.x] = gcnt[threadIdx.x];
    __syncthreads();
    for (int i = threadIdx.x; i < KC; i += 256) {
        float sA = 0.f, sO = 0.f;
        #pragma unroll
        for (int r = 0; r < NREP; ++r) { sA += partA[r * KC + i]; sO += partO[r * KC + i]; }
        int k = i >> 8, c = i & 255;
        float cn = cntS[k];
        bool pr = cn > 0.f;
        float d = pr ? cn : 1.f;
        anc[k * 260 + c] = pr ? sA / d : 0.f;
        con[k * 260 + c] = pr ? sO / d : 0.f;
    }
    __syncthreads();
    // adc[k][j] = dot(anc_k, contrast_j)/T,  contrast = [anc; con]
    for (int pair = threadIdx.x; pair < NUMC * 2 * NUMC; pair += 256) {
        int k = pair / (2 * NUMC);
        int j = pair % (2 * NUMC);
        const float* ar = anc + k * 260;
        const float* br = (j < NUMC) ? (anc + j * 260) : (con + (j - NUMC) * 260);
        float s = 0.f;
        for (int c = 0; c < CCH; c += 4) {
            float4 a4 = *(const float4*)(ar + c);
            float4 b4 = *(const float4*)(br + c);
            s += a4.x * b4.x + a4.y * b4.y + a4.z * b4.z + a4.w * b4.w;
        }
        adc[k * 44 + j] = s / 0.07f;
    }
    __syncthreads();
    if (threadIdx.x < NUMC) {
        int k = threadIdx.x;
        bool pr = cntS[k] > 0.f;
        float neg = 0.f;       // faithful to source — negatives use UNshifted logits
        float mx = -1e30f;
        for (int j = 0; j < 2 * NUMC; ++j) {
            int cj = (j < NUMC) ? j : (j - NUMC);
            bool cp = cntS[cj] > 0.f;
            float v = adc[k * 44 + j];
            if (cp) {
                if (v > mx) mx = v;
                if (j != k && j != NUMC + k) neg += expf(v);
            }
        }
        float sh = adc[k * 44 + NUMC + k] - mx;
        float rl = -(sh - logf(expf(sh) + neg));
        rowloss[k] = pr ? rl : 0.f;
        rowvalid[k] = pr ? 1.f : 0.f;
    }
    __syncthreads();
    if (threadIdx.x == 0) {
        float s = 0.f, v = 0.f;
        for (int kk = 0; kk < NUMC; ++kk) { s += rowloss[kk]; v += rowvalid[kk]; }
        out[0] = s / fmaxf(v, 1.f);
    }
}

// ---------------- launch ----------------
extern "C" void kernel_launch(void* const* d_in, const int* in_sizes, int n_in,
                              void* d_out, int out_size, void* d_ws, size_t ws_size,
                              hipStream_t stream) {
    const int*   labels      = (const int*)  d_in[0];
    const float* feats_old   = (const float*)d_in[1];
    const float* feats       = (const float*)d_in[2];
    const float* outputs_old = (const float*)d_in[3];
    // d_in[4] (outputs) and d_in[5] (prototypes) are unused by the reference math.

    float* ws    = (float*)d_ws;
    int*   lab   = (int*)ws;                   // [131072]
    float* partA = ws + 131072;                // [16*5376]
    float* partO = partA + NREP * KC;          // [16*5376]
    float* gcnt  = partO + NREP * KC;          // [21]

    hipMemsetAsync(partA, 0, (size_t)(2 * NREP * KC + NUMC) * sizeof(float), stream);

    k_labels<<<NPIX / 256, 256, 0, stream>>>(labels, outputs_old, lab, gcnt);
    k_msum  <<<1024, 256, 0, stream>>>(feats, feats_old, lab, partA, partO);
    k_final <<<1, 256, 0, stream>>>(partA, partO, gcnt, (float*)d_out);
}